// Round 18
// baseline (1332.955 us; speedup 1.0000x reference)
//
#include <hip/hip_runtime.h>
#include <hip/hip_bf16.h>
#include <hip/hip_fp16.h>
#include <cstddef>
#include <cstdint>

// Problem constants (from reference)
#define Nn 50000
#define Ee 800000
#define Tt 8
#define Ff 128
#define Hh 128
#define Cc 10
#define Gg 64
#define NT 400000    // Tt * Nn

typedef __attribute__((ext_vector_type(8))) short bf16x8;
typedef __attribute__((ext_vector_type(4))) float f32x4;
typedef __attribute__((ext_vector_type(8))) _Float16 f16x8;

__device__ inline unsigned short f2bf(float x) {
    __hip_bfloat16 b = __float2bfloat16(x);
    return *reinterpret_cast<unsigned short*>(&b);
}
__device__ inline float bf2f(unsigned short u) {
    __hip_bfloat16 b = *reinterpret_cast<__hip_bfloat16*>(&u);
    return __bfloat162float(b);
}
__device__ inline void split2(float x, unsigned short& h, unsigned short& l) {
    h = f2bf(x);
    l = f2bf(x - bf2f(h));
}

// ---------------------------------------------------------------------------
// Degree / normalization / CSR build
// ---------------------------------------------------------------------------
__global__ __launch_bounds__(256) void count_deg_kernel(const int* __restrict__ dst,
                                                        int* __restrict__ counts) {
    int e = blockIdx.x * 256 + threadIdx.x;
    if (e < Ee) atomicAdd(&counts[dst[e]], 1);
}

__global__ __launch_bounds__(256) void dis_kernel(const int* __restrict__ counts,
                                                  float* __restrict__ dis) {
    int i = blockIdx.x * 256 + threadIdx.x;
    if (i < Nn) dis[i] = 1.0f / sqrtf((float)counts[i] + 1.0f);
}

__global__ __launch_bounds__(256) void scan_block_kernel(const int* __restrict__ counts,
                                                         int* __restrict__ incl,
                                                         int* __restrict__ blksum) {
    __shared__ int s[256];
    int t = threadIdx.x;
    int i = blockIdx.x * 256 + t;
    int v = (i < Nn) ? counts[i] : 0;
    s[t] = v;
    __syncthreads();
    #pragma unroll
    for (int d = 1; d < 256; d <<= 1) {
        int add = (t >= d) ? s[t - d] : 0;
        __syncthreads();
        s[t] += add;
        __syncthreads();
    }
    if (i < Nn) incl[i] = s[t];
    if (t == 255) blksum[blockIdx.x] = s[255];
}

__global__ __launch_bounds__(256) void scan_tops_kernel(int* __restrict__ blksum, int nb) {
    __shared__ int s[256];
    int t = threadIdx.x;
    int v = (t < nb) ? blksum[t] : 0;
    s[t] = v;
    __syncthreads();
    #pragma unroll
    for (int d = 1; d < 256; d <<= 1) {
        int add = (t >= d) ? s[t - d] : 0;
        __syncthreads();
        s[t] += add;
        __syncthreads();
    }
    if (t < nb) blksum[t] = s[t] - v;  // exclusive
}

__global__ __launch_bounds__(256) void scan_fix_kernel(const int* __restrict__ counts,
                                                       const int* __restrict__ incl,
                                                       const int* __restrict__ blksum,
                                                       int* __restrict__ off) {
    int i = blockIdx.x * 256 + threadIdx.x;
    if (i < Nn) off[i] = incl[i] - counts[i] + blksum[i >> 8];
}

__global__ __launch_bounds__(256) void fill_csr_kernel(const int* __restrict__ src,
                                                       const int* __restrict__ dst,
                                                       const float* __restrict__ dis,
                                                       const int* __restrict__ off,
                                                       int* __restrict__ cursor,
                                                       int* __restrict__ csr_src,
                                                       float* __restrict__ csr_w) {
    int e = blockIdx.x * 256 + threadIdx.x;
    if (e >= Ee) return;
    int s = src[e], d = dst[e];
    int slot = off[d] + atomicAdd(&cursor[d], 1);
    csr_src[slot] = s;
    csr_w[slot] = dis[s] * dis[d];
}

// ---------------------------------------------------------------------------
// Weight split kernels (fp32 -> bf16 hi/lo, layout B^T [col][K])
// ---------------------------------------------------------------------------
__global__ __launch_bounds__(256) void wsplit_kernel(const float* __restrict__ W,
                                                     unsigned short* __restrict__ bh,
                                                     unsigned short* __restrict__ bl, int n) {
    int i = blockIdx.x * 256 + threadIdx.x;
    if (i >= n) return;
    unsigned short h, l;
    split2(W[i], h, l);
    bh[i] = h;
    bl[i] = l;
}

__global__ __launch_bounds__(256) void wgcnT_kernel(const float* __restrict__ W,
                                                    unsigned short* __restrict__ bh,
                                                    unsigned short* __restrict__ bl) {
    int i = blockIdx.x * 256 + threadIdx.x;
    if (i >= 128 * 128) return;
    int f = i >> 7, hc = i & 127;
    unsigned short h, l;
    split2(W[i], h, l);
    bh[hc * 128 + f] = h;
    bl[hc * 128 + f] = l;
}

// ---------------------------------------------------------------------------
// xw GEMM: xwp[(n*8+t)][128] (fp16) = x_seq[(t*Nn+n)][128] @ W_gcn.
// ---------------------------------------------------------------------------
__global__ __launch_bounds__(256) void xw_gemm(const float* __restrict__ X,
                                               const unsigned short* __restrict__ BTh,
                                               const unsigned short* __restrict__ BTl,
                                               __half* __restrict__ Cout) {
    __shared__ __align__(16) char lds[32768];
    char* pAh = lds;
    char* pAl = lds + 16384;
    const int bm = blockIdx.x * 128;
    const int tid = threadIdx.x;
    const int wid = tid >> 6, lane = tid & 63;
    const int wr = wid >> 1, wc = wid & 1;
    const int l15 = lane & 15, l4 = lane >> 4;

    f32x4 acc[4][4] = {};

    for (int kh = 0; kh < 2; ++kh) {
        if (kh) __syncthreads();
        #pragma unroll
        for (int i = 0; i < 8; ++i) {
            int idx = tid + i * 256;
            int row = idx >> 4;
            int k4 = idx & 15;
            float4 v = *(const float4*)(X + (size_t)(bm + row) * 128 + kh * 64 + k4 * 4);
            ushort4 h, l;
            split2(v.x, h.x, l.x);
            split2(v.y, h.y, l.y);
            split2(v.z, h.z, l.z);
            split2(v.w, h.w, l.w);
            int off = row * 128 + ((k4 * 8) ^ ((row & 7) << 4));
            *(ushort4*)(pAh + off) = h;
            *(ushort4*)(pAl + off) = l;
        }
        __syncthreads();

        #pragma unroll
        for (int kq = 0; kq < 2; ++kq) {
            bf16x8 a_h[4], a_l[4], b_h[4], b_l[4];
            const int kbase = kq * 64 + l4 * 16;
            #pragma unroll
            for (int m = 0; m < 4; ++m) {
                const int r = wr * 64 + m * 16 + l15;
                const int byteo = r * 128 + (kbase ^ ((r & 7) << 4));
                a_h[m] = *(const bf16x8*)(pAh + byteo);
                a_l[m] = *(const bf16x8*)(pAl + byteo);
            }
            #pragma unroll
            for (int n = 0; n < 4; ++n) {
                const int col = wc * 64 + n * 16 + l15;
                const size_t bo = (size_t)col * 128 + kh * 64 + kq * 32 + l4 * 8;
                b_h[n] = *(const bf16x8*)(BTh + bo);
                b_l[n] = *(const bf16x8*)(BTl + bo);
            }
            #pragma unroll
            for (int m = 0; m < 4; ++m)
                #pragma unroll
                for (int n = 0; n < 4; ++n) {
                    acc[m][n] = __builtin_amdgcn_mfma_f32_16x16x32_bf16(a_h[m], b_h[n],
                                                                        acc[m][n], 0, 0, 0);
                    acc[m][n] = __builtin_amdgcn_mfma_f32_16x16x32_bf16(a_h[m], b_l[n],
                                                                        acc[m][n], 0, 0, 0);
                    acc[m][n] = __builtin_amdgcn_mfma_f32_16x16x32_bf16(a_l[m], b_h[n],
                                                                        acc[m][n], 0, 0, 0);
                }
        }
    }

    // epilogue: remap GEMM row r = t*Nn + n  ->  output row n*8 + t (fp16)
    #pragma unroll
    for (int m = 0; m < 4; ++m) {
        const int row = bm + wr * 64 + m * 16 + l4 * 4;
        #pragma unroll
        for (int q = 0; q < 4; ++q) {
            const int r = row + q;
            const int tt = r / Nn;
            const int nn = r - tt * Nn;
            __half* outrow = Cout + ((size_t)nn * 8 + tt) * 128;
            #pragma unroll
            for (int n = 0; n < 4; ++n) {
                const int col = wc * 64 + n * 16 + l15;
                outrow[col] = __float2half(acc[m][n][q]);
            }
        }
    }
}

// ---------------------------------------------------------------------------
// FUSED aggregation + gx GEMM. One block = 8 nodes = 64 rows.
// Phase A: gather xwp 2KB fp16 node-blocks; depth-4 pipeline; fp32 acc.
// Phase B: gx = gcn @ W_ih^T + b_ih. Epilogue stages each 32-row half of
//          the swizzled gx tile in LDS, then copies out as coalesced 16B
//          stores -> full-line coverage, no 2-byte-store RFO amplification.
// ---------------------------------------------------------------------------
__global__ __launch_bounds__(256, 1) void aggx_kernel(const __half* __restrict__ xwp,
                                                      const float* __restrict__ dis,
                                                      const int* __restrict__ off,
                                                      const int* __restrict__ counts,
                                                      const int* __restrict__ csr_src,
                                                      const float* __restrict__ csr_w,
                                                      const float* __restrict__ b_gcn,
                                                      const unsigned short* __restrict__ BTh,
                                                      const unsigned short* __restrict__ BTl,
                                                      const float* __restrict__ bias,
                                                      __half* __restrict__ gx16) {
    __shared__ __align__(16) char lds[32768];  // gcn hi 16KB + lo 16KB | stg 24KB
    char* pAh = lds;
    char* pAl = lds + 16384;
    const int n0 = blockIdx.x * 8;
    const int tid = threadIdx.x;
    const int wid = tid >> 6, lane = tid & 63;
    const int l15 = lane & 15, l4 = lane >> 4;

    // ---- Phase A: aggregate 2 nodes per wave (fp16 gather, fp32 acc) ----
    for (int nl = 0; nl < 2; ++nl) {
        const int n = n0 + wid * 2 + nl;
        const float dv = dis[n];
        const float dsq = dv * dv;
        float acc0[8], acc1[8];
        {
            const __half* bn_ = xwp + (size_t)n * 1024;
            f16x8 s0v = *(const f16x8*)(bn_ + lane * 8);
            f16x8 s1v = *(const f16x8*)(bn_ + 512 + lane * 8);
            #pragma unroll
            for (int j = 0; j < 8; ++j) {
                acc0[j] = (float)s0v[j] * dsq;
                acc1[j] = (float)s1v[j] * dsq;
            }
        }

        const int s0 = off[n];
        const int cnt = counts[n];
        for (int base = 0; base < cnt; base += 64) {
            const int m = min(64, cnt - base);
            int idxv = 0;
            float wvv = 0.f;
            {
                int j = base + lane;
                if (j < cnt) {
                    idxv = csr_src[s0 + j];
                    wvv = csr_w[s0 + j];
                }
            }
            // depth-4 pipeline: edges A (even) and B (odd), each prefetch +2
            int sA = __shfl(idxv, 0);
            float wA = __shfl(wvv, 0);
            const __half* pA = xwp + (size_t)sA * 1024;
            f16x8 a0 = *(const f16x8*)(pA + lane * 8);
            f16x8 a1 = *(const f16x8*)(pA + 512 + lane * 8);
            f16x8 b0 = a0, b1 = a1;
            float wB = 0.f;
            if (1 < m) {
                int sB = __shfl(idxv, 1);
                wB = __shfl(wvv, 1);
                const __half* pB = xwp + (size_t)sB * 1024;
                b0 = *(const f16x8*)(pB + lane * 8);
                b1 = *(const f16x8*)(pB + 512 + lane * 8);
            }
            for (int k = 0; k < m; k += 2) {
                f16x8 ua0 = a0, ua1 = a1;
                const float uwa = wA;
                if (k + 2 < m) {
                    int sN = __shfl(idxv, k + 2);
                    wA = __shfl(wvv, k + 2);
                    const __half* pN = xwp + (size_t)sN * 1024;
                    a0 = *(const f16x8*)(pN + lane * 8);
                    a1 = *(const f16x8*)(pN + 512 + lane * 8);
                }
                #pragma unroll
                for (int j = 0; j < 8; ++j) {
                    acc0[j] = fmaf((float)ua0[j], uwa, acc0[j]);
                    acc1[j] = fmaf((float)ua1[j], uwa, acc1[j]);
                }
                if (k + 1 < m) {
                    f16x8 ub0 = b0, ub1 = b1;
                    const float uwb = wB;
                    if (k + 3 < m) {
                        int sN = __shfl(idxv, k + 3);
                        wB = __shfl(wvv, k + 3);
                        const __half* pN = xwp + (size_t)sN * 1024;
                        b0 = *(const f16x8*)(pN + lane * 8);
                        b1 = *(const f16x8*)(pN + 512 + lane * 8);
                    }
                    #pragma unroll
                    for (int j = 0; j < 8; ++j) {
                        acc0[j] = fmaf((float)ub0[j], uwb, acc0[j]);
                        acc1[j] = fmaf((float)ub1[j], uwb, acc1[j]);
                    }
                }
            }
        }

        // relu + bias, split, write into LDS (swizzled). chunk p covers
        // t = p*4 + (lane>>4), cols c0..c0+7 with c0 = (lane&15)*8.
        #pragma unroll
        for (int p = 0; p < 2; ++p) {
            const int t = p * 4 + l4;
            const int c0 = l15 * 8;
            float4 bbA = *(const float4*)(b_gcn + c0);
            float4 bbB = *(const float4*)(b_gcn + c0 + 4);
            const float* ap = p ? acc1 : acc0;
            float v[8];
            v[0] = fmaxf(ap[0] + bbA.x, 0.f);
            v[1] = fmaxf(ap[1] + bbA.y, 0.f);
            v[2] = fmaxf(ap[2] + bbA.z, 0.f);
            v[3] = fmaxf(ap[3] + bbA.w, 0.f);
            v[4] = fmaxf(ap[4] + bbB.x, 0.f);
            v[5] = fmaxf(ap[5] + bbB.y, 0.f);
            v[6] = fmaxf(ap[6] + bbB.z, 0.f);
            v[7] = fmaxf(ap[7] + bbB.w, 0.f);
            ushort4 oh0, ol0, oh1, ol1;
            split2(v[0], oh0.x, ol0.x);
            split2(v[1], oh0.y, ol0.y);
            split2(v[2], oh0.z, ol0.z);
            split2(v[3], oh0.w, ol0.w);
            split2(v[4], oh1.x, ol1.x);
            split2(v[5], oh1.y, ol1.y);
            split2(v[6], oh1.z, ol1.z);
            split2(v[7], oh1.w, ol1.w);
            const int r = (wid * 2 + nl) * 8 + t;        // local row, r&7 == t
            const int o1 = r * 256 + ((c0 * 2) ^ (t << 4));
            *(ushort4*)(pAh + o1) = oh0;
            *(ushort4*)(pAh + o1 + 8) = oh1;
            *(ushort4*)(pAl + o1) = ol0;
            *(ushort4*)(pAl + o1 + 8) = ol1;
        }
    }
    __syncthreads();

    // ---- Phase B: gx = gcn @ W_ih^T + b_ih, wave owns 96 cols ----
    f32x4 acc[4][6] = {};
    const int wc0 = wid * 96;
    #pragma unroll
    for (int kq = 0; kq < 4; ++kq) {
        bf16x8 a_h[4], a_l[4];
        const int kbase = kq * 64 + l4 * 16;
        #pragma unroll
        for (int m = 0; m < 4; ++m) {
            const int r = m * 16 + l15;
            const int byteo = r * 256 + (kbase ^ ((r & 7) << 4));
            a_h[m] = *(const bf16x8*)(pAh + byteo);
            a_l[m] = *(const bf16x8*)(pAl + byteo);
        }
        #pragma unroll
        for (int n = 0; n < 6; ++n) {
            const int col = wc0 + n * 16 + l15;
            const size_t bo = (size_t)col * 128 + kq * 32 + l4 * 8;
            bf16x8 b_h = *(const bf16x8*)(BTh + bo);
            bf16x8 b_l = *(const bf16x8*)(BTl + bo);
            #pragma unroll
            for (int m = 0; m < 4; ++m) {
                acc[m][n] = __builtin_amdgcn_mfma_f32_16x16x32_bf16(a_h[m], b_h,
                                                                    acc[m][n], 0, 0, 0);
                acc[m][n] = __builtin_amdgcn_mfma_f32_16x16x32_bf16(a_h[m], b_l,
                                                                    acc[m][n], 0, 0, 0);
                acc[m][n] = __builtin_amdgcn_mfma_f32_16x16x32_bf16(a_l[m], b_h,
                                                                    acc[m][n], 0, 0, 0);
            }
        }
    }

    // epilogue: stage swizzled gx tile halves (32 rows = 24KB) in LDS,
    // copy out as coalesced 16B stores. stg layout: [tt][nl(0..3)][768B].
    char* stg = lds;
    #pragma unroll
    for (int half = 0; half < 2; ++half) {
        __syncthreads();  // LDS (pA / previous stg) reads complete
        #pragma unroll
        for (int mm = 0; mm < 2; ++mm) {
            const int m = half * 2 + mm;
            #pragma unroll
            for (int n = 0; n < 6; ++n) {
                const int col = wc0 + n * 16 + l15;
                const float bb = bias[col];
                #pragma unroll
                for (int q = 0; q < 4; ++q) {
                    const int lr = m * 16 + l4 * 4 + q;
                    const int tt = lr & 7;
                    const int nl = (lr >> 3) & 3;       // node_local within half
                    const int node7 = half * 4 + nl;    // node & 7
                    const int cb = (col * 2) ^ (node7 << 4);
                    *(__half*)(stg + tt * 3072 + nl * 768 + cb) =
                        __float2half(acc[m][n][q] + bb);
                }
            }
        }
        __syncthreads();
        // copy out: 8 chunks of 3KB, each contiguous in gx16
        for (int i = tid; i < 1536; i += 256) {
            const int tt = i / 192;
            const int o = (i - tt * 192) * 16;
            f32x4 v = *(const f32x4*)(stg + tt * 3072 + o);
            *(f32x4*)((char*)gx16 + ((size_t)tt * Nn + n0 + half * 4) * 768 + o) = v;
        }
    }
}

// ---------------------------------------------------------------------------
// GRU v7: block = 64 nodes, 4 waves, register-local gate, h state in LDS,
// two node-groups per step; launch_bounds(256,1) -> no VGPR spills.
// ---------------------------------------------------------------------------
__global__ __launch_bounds__(256, 1) void gru_kernel(const unsigned short* __restrict__ BTh,
                                                     const unsigned short* __restrict__ BTl,
                                                     const __half* __restrict__ gx,
                                                     const float* __restrict__ b_hh,
                                                     float* __restrict__ hbuf) {
    __shared__ __align__(16) char lds[81920];  // hHi 16K | hLo 16K | gxS 48K
    char* pHh = lds;
    char* pHl = lds + 16384;
    char* gxS = lds + 32768;
    const int tid = threadIdx.x;
    const int wid = tid >> 6, lane = tid & 63;
    const int l15 = lane & 15, l4 = lane >> 4;
    const int n0 = blockIdx.x * 64;

    float bh[3][2];
    #pragma unroll
    for (int g = 0; g < 3; ++g)
        #pragma unroll
        for (int tt = 0; tt < 2; ++tt)
            bh[g][tt] = b_hh[g * 128 + wid * 32 + tt * 16 + l15];

    #define ISSUE_GX(T)                                                                  \
        {                                                                                \
            const char* srcb = (const char*)(gx + ((size_t)(T) * Nn + n0) * 384);        \
            _Pragma("unroll")                                                            \
            for (int i = 0; i < 12; ++i) {                                               \
                const int o = i * 4096 + tid * 16;                                       \
                __builtin_amdgcn_global_load_lds(                                        \
                    (const __attribute__((address_space(1))) void*)(srcb + o),           \
                    (__attribute__((address_space(3))) void*)(gxS + o), 16, 0, 0);       \
            }                                                                            \
        }

    // ---- t = 0: gh = 0 (h=0); write h(0) to LDS only ----
    ISSUE_GX(0);
    __syncthreads();
    #pragma unroll
    for (int m = 0; m < 4; ++m) {
        #pragma unroll
        for (int q = 0; q < 4; ++q) {
            const int nl = m * 16 + l4 * 4 + q;
            const char* rp = gxS + nl * 768;
            const int key = (nl & 7) << 4;
            #pragma unroll
            for (int tt = 0; tt < 2; ++tt) {
                const int c0 = wid * 32 + tt * 16 + l15;
                float xr = __half2float(*(const __half*)(rp + ((2 * c0) ^ key)));
                float xz = __half2float(*(const __half*)(rp + ((2 * (c0 + 128)) ^ key)));
                float xn = __half2float(*(const __half*)(rp + ((2 * (c0 + 256)) ^ key)));
                float rg = 1.f / (1.f + expf(-(xr + bh[0][tt])));
                float zg = 1.f / (1.f + expf(-(xz + bh[1][tt])));
                float ng = tanhf(xn + rg * bh[2][tt]);
                float hnew = (1.f - zg) * ng;
                unsigned short sh, sl;
                split2(hnew, sh, sl);
                const int byteo = nl * 256 + ((2 * c0) ^ key);
                *(unsigned short*)(pHh + byteo) = sh;
                *(unsigned short*)(pHl + byteo) = sl;
            }
        }
    }

    for (int t = 1; t < Tt; ++t) {
        __syncthreads();  // gates of t-1 done (gxS reads retired, h(t-1) complete)
        ISSUE_GX(t);      // async: lands during group-0 MFMA

        const int wlast = (t == Tt - 1);
        #pragma unroll
        for (int grp = 0; grp < 2; ++grp) {
            f32x4 acc[2][6];
            #pragma unroll
            for (int m = 0; m < 2; ++m)
                #pragma unroll
                for (int j = 0; j < 6; ++j) acc[m][j] = (f32x4){0.f, 0.f, 0.f, 0.f};
            const int akey = (l15 & 7) << 4;
            #pragma unroll
            for (int kq = 0; kq < 4; ++kq) {
                bf16x8 a_h[2], a_l[2];
                #pragma unroll
                for (int m = 0; m < 2; ++m) {
                    const int ab = ((grp * 2 + m) * 16 + l15) * 256 +
                                   ((kq * 64 + l4 * 16) ^ akey);
                    a_h[m] = *(const bf16x8*)(pHh + ab);
                    a_l[m] = *(const bf16x8*)(pHl + ab);
                }
                #pragma unroll
                for (int j = 0; j < 6; ++j) {
                    const int g = j >> 1, tt = j & 1;
                    const int col = g * 128 + wid * 32 + tt * 16 + l15;
                    const size_t bo = (size_t)col * 128 + kq * 32 + l4 * 8;
                    bf16x8 b_h = *(const bf16x8*)(BTh + bo);
                    bf16x8 b_l = *(const bf16x8*)(BTl + bo);
                    #pragma unroll
                    for (int m = 0; m < 2; ++m) {
                        acc[m][j] = __builtin_amdgcn_mfma_f32_16x16x32_bf16(a_h[m], b_h,
                                                                           acc[m][j], 0, 0, 0);
                        acc[m][j] = __builtin_amdgcn_mfma_f32_16x16x32_bf16(a_h[m], b_l,
                                                                           acc[m][j], 0, 0, 0);
                        acc[m][j] = __builtin_amdgcn_mfma_f32_16x16x32_bf16(a_l[m], b_h,
                                                                           acc[m][j], 0, 0, 0);
                    }
                }
            }
            __syncthreads();  // group's MFMA h-reads done; (grp 0) gx landed

            #pragma unroll
            for (int m = 0; m < 2; ++m) {
                #pragma unroll
                for (int q = 0; q < 4; ++q) {
                    const int nl = (grp * 2 + m) * 16 + l4 * 4 + q;
                    const char* rp = gxS + nl * 768;
                    const int key = (nl & 7) << 4;
                    #pragma unroll
                    for (int tt = 0; tt < 2; ++tt) {
                        const int c0 = wid * 32 + tt * 16 + l15;
                        const int byteo = nl * 256 + ((2 * c0) ^ key);
                        float xr = __half2float(*(const __half*)(rp + ((2 * c0) ^ key)));
                        float xz = __half2float(*(const __half*)(rp + ((2 * (c0 + 128)) ^ key)));
                        float xn = __half2float(*(const __half*)(rp + ((2 * (c0 + 256)) ^ key)));
                        float h_old = bf2f(*(const unsigned short*)(pHh + byteo)) +
                                      bf2f(*(const unsigned short*)(pHl + byteo));
                        float ghr = acc[m][0 + tt][q] + bh[0][tt];
                        float ghz = acc[m][2 + tt][q] + bh[1][tt];
                        float ghn = acc[m][4 + tt][q] + bh[2][tt];
                        float rg = 1.f / (1.f + expf(-(xr + ghr)));
                        float zg = 1.f / (1.f + expf(-(xz + ghz)));
                        float ng = tanhf(xn + rg * ghn);
                        float hnew = (1.f - zg) * ng + zg * h_old;
                        if (!wlast) {
                            unsigned short sh, sl;
                            split2(hnew, sh, sl);
                            *(unsigned short*)(pHh + byteo) = sh;
                            *(unsigned short*)(pHl + byteo) = sl;
                        } else {
                            const int row = n0 + nl;
                            if (row < Nn) hbuf[(size_t)row * 128 + c0] = hnew;
                        }
                    }
                }
            }
        }
    }
    #undef ISSUE_GX
}

// ---------------------------------------------------------------------------
// Graph sizes by binary search on the SORTED batch array
// ---------------------------------------------------------------------------
__global__ void gcount_bs_kernel(const int* __restrict__ batch, float* __restrict__ ginv) {
    int g = threadIdx.x;
    if (g >= Gg) return;
    int lo = 0, hi = Nn;
    while (lo < hi) {
        int m = (lo + hi) >> 1;
        if (batch[m] < g) lo = m + 1; else hi = m;
    }
    int start = lo;
    lo = 0; hi = Nn;
    while (lo < hi) {
        int m = (lo + hi) >> 1;
        if (batch[m] <= g) lo = m + 1; else hi = m;
    }
    ginv[g] = 1.f / fmaxf((float)(lo - start), 1.f);
}

// ---------------------------------------------------------------------------
// FC (h @ W_fc + b_fc) fused with mean pooling via atomics
// ---------------------------------------------------------------------------
__global__ __launch_bounds__(256) void fc_pool_kernel(const float* __restrict__ h,
                                                      const float* __restrict__ Wfc,
                                                      const float* __restrict__ bfc,
                                                      const int* __restrict__ batch,
                                                      const float* __restrict__ ginv,
                                                      float* __restrict__ out) {
    __shared__ float hs[16][128];
    __shared__ float wf[128][10];
    __shared__ float bf[10];
    int b0 = blockIdx.x * 16;
    int t = threadIdx.x;
    for (int i = t; i < 128 * 10; i += 256) wf[i / 10][i % 10] = Wfc[i];
    if (t < 10) bf[t] = bfc[t];
    for (int i = t; i < 16 * 32; i += 256) {
        int r = i >> 5, c4 = i & 31;
        int row = b0 + r;
        float4 v = make_float4(0.f, 0.f, 0.f, 0.f);
        if (row < Nn) v = *(const float4*)(h + (size_t)row * 128 + c4 * 4);
        *(float4*)(&hs[r][c4 * 4]) = v;
    }
    __syncthreads();
    if (t < 160) {
        int r = t / 10, c = t % 10;
        int row = b0 + r;
        if (row < Nn) {
            float acc = bf[c];
            #pragma unroll
            for (int k = 0; k < 128; ++k) acc = fmaf(hs[r][k], wf[k][c], acc);
            int g = batch[row];
            atomicAdd(out + g * 10 + c, acc * ginv[g]);
        }
    }
}

// ---------------------------------------------------------------------------
// Launch
// ---------------------------------------------------------------------------
extern "C" void kernel_launch(void* const* d_in, const int* in_sizes, int n_in,
                              void* d_out, int out_size, void* d_ws, size_t ws_size,
                              hipStream_t stream) {
    const float* x_seq = (const float*)d_in[0];
    const int*   eidx  = (const int*)d_in[1];
    const int*   batch = (const int*)d_in[2];
    const float* W_gcn = (const float*)d_in[3];
    const float* b_gcn = (const float*)d_in[4];
    const float* W_ih  = (const float*)d_in[5];
    const float* W_hh  = (const float*)d_in[6];
    const float* b_ih  = (const float*)d_in[7];
    const float* b_hh  = (const float*)d_in[8];
    const float* W_fc  = (const float*)d_in[9];
    const float* b_fc  = (const float*)d_in[10];
    const int* src = eidx;
    const int* dst = eidx + Ee;
    float* out = (float*)d_out;

    size_t woff = 0;
    auto alloc = [&](size_t bytes) -> void* {
        void* p = (char*)d_ws + woff;
        woff = (woff + bytes + 255) & ~(size_t)255;
        return p;
    };
    int*   counts  = (int*)alloc(Nn * 4);
    int*   cursor  = (int*)alloc(Nn * 4);
    int*   incl    = (int*)alloc(Nn * 4);
    int*   blksum  = (int*)alloc(256 * 4);
    int*   offx    = (int*)alloc(Nn * 4);
    int*   csr_src = (int*)alloc(Ee * 4);
    float* csr_w   = (float*)alloc(Ee * 4);
    float* dis     = (float*)alloc(Nn * 4);
    unsigned short* wg_hi  = (unsigned short*)alloc(128 * 128 * 2);
    unsigned short* wg_lo  = (unsigned short*)alloc(128 * 128 * 2);
    unsigned short* wih_hi = (unsigned short*)alloc(384 * 128 * 2);
    unsigned short* wih_lo = (unsigned short*)alloc(384 * 128 * 2);
    unsigned short* whh_hi = (unsigned short*)alloc(384 * 128 * 2);
    unsigned short* whh_lo = (unsigned short*)alloc(384 * 128 * 2);
    float* ginv = (float*)alloc(256);
    __half* xwp  = (__half*)alloc((size_t)NT * 128 * 2);  // 102.4 MB fp16, [n][t][128]
    __half* gx16 = (__half*)alloc((size_t)NT * 384 * 2);  // 307.2 MB, [t][n][384] swz
    float* hbuf  = (float*)alloc((size_t)Nn * 128 * 4);   // 25.6 MB (also DMA tail pad)

    hipMemsetAsync(counts, 0, Nn * 4, stream);
    hipMemsetAsync(cursor, 0, Nn * 4, stream);
    hipMemsetAsync(d_out, 0, (size_t)Gg * Cc * 4, stream);

    const int nbN = (Nn + 255) / 256;
    const int nbE = (Ee + 255) / 256;

    count_deg_kernel<<<nbE, 256, 0, stream>>>(dst, counts);
    dis_kernel<<<nbN, 256, 0, stream>>>(counts, dis);
    scan_block_kernel<<<nbN, 256, 0, stream>>>(counts, incl, blksum);
    scan_tops_kernel<<<1, 256, 0, stream>>>(blksum, nbN);
    scan_fix_kernel<<<nbN, 256, 0, stream>>>(counts, incl, blksum, offx);
    fill_csr_kernel<<<nbE, 256, 0, stream>>>(src, dst, dis, offx, cursor, csr_src, csr_w);

    wsplit_kernel<<<(384 * 128 + 255) / 256, 256, 0, stream>>>(W_ih, wih_hi, wih_lo, 384 * 128);
    wsplit_kernel<<<(384 * 128 + 255) / 256, 256, 0, stream>>>(W_hh, whh_hi, whh_lo, 384 * 128);
    wgcnT_kernel<<<(128 * 128 + 255) / 256, 256, 0, stream>>>(W_gcn, wg_hi, wg_lo);
    gcount_bs_kernel<<<1, 64, 0, stream>>>(batch, ginv);

    // xw for all T, output [n][t][128] fp16 (L3-resident gather source)
    xw_gemm<<<NT / 128, 256, 0, stream>>>(x_seq, wg_hi, wg_lo, xwp);
    // fused aggregation + gx GEMM; LDS-staged coalesced gx writes
    aggx_kernel<<<Nn / 8, 256, 0, stream>>>(xwp, dis, offx, counts, csr_src, csr_w,
                                            b_gcn, wih_hi, wih_lo, b_ih, gx16);
    // GRU v7
    gru_kernel<<<(Nn + 63) / 64, 256, 0, stream>>>(whh_hi, whh_lo, gx16, b_hh, hbuf);

    fc_pool_kernel<<<(Nn + 15) / 16, 256, 0, stream>>>(hbuf, W_fc, b_fc, batch, ginv, out);
}

// Round 19
// 1150.718 us; speedup vs baseline: 1.1584x; 1.1584x over previous
//
#include <hip/hip_runtime.h>
#include <hip/hip_bf16.h>
#include <hip/hip_fp16.h>
#include <cstddef>
#include <cstdint>

// Problem constants (from reference)
#define Nn 50000
#define Ee 800000
#define Tt 8
#define Ff 128
#define Hh 128
#define Cc 10
#define Gg 64
#define NT 400000    // Tt * Nn

typedef __attribute__((ext_vector_type(8))) short bf16x8;
typedef __attribute__((ext_vector_type(4))) float f32x4;
typedef __attribute__((ext_vector_type(8))) _Float16 f16x8;

__device__ inline unsigned short f2bf(float x) {
    __hip_bfloat16 b = __float2bfloat16(x);
    return *reinterpret_cast<unsigned short*>(&b);
}
__device__ inline float bf2f(unsigned short u) {
    __hip_bfloat16 b = *reinterpret_cast<__hip_bfloat16*>(&u);
    return __bfloat162float(b);
}
__device__ inline void split2(float x, unsigned short& h, unsigned short& l) {
    h = f2bf(x);
    l = f2bf(x - bf2f(h));
}

// ---------------------------------------------------------------------------
// Degree / normalization / CSR build
// ---------------------------------------------------------------------------
__global__ __launch_bounds__(256) void count_deg_kernel(const int* __restrict__ dst,
                                                        int* __restrict__ counts) {
    int e = blockIdx.x * 256 + threadIdx.x;
    if (e < Ee) atomicAdd(&counts[dst[e]], 1);
}

__global__ __launch_bounds__(256) void dis_kernel(const int* __restrict__ counts,
                                                  float* __restrict__ dis) {
    int i = blockIdx.x * 256 + threadIdx.x;
    if (i < Nn) dis[i] = 1.0f / sqrtf((float)counts[i] + 1.0f);
}

__global__ __launch_bounds__(256) void scan_block_kernel(const int* __restrict__ counts,
                                                         int* __restrict__ incl,
                                                         int* __restrict__ blksum) {
    __shared__ int s[256];
    int t = threadIdx.x;
    int i = blockIdx.x * 256 + t;
    int v = (i < Nn) ? counts[i] : 0;
    s[t] = v;
    __syncthreads();
    #pragma unroll
    for (int d = 1; d < 256; d <<= 1) {
        int add = (t >= d) ? s[t - d] : 0;
        __syncthreads();
        s[t] += add;
        __syncthreads();
    }
    if (i < Nn) incl[i] = s[t];
    if (t == 255) blksum[blockIdx.x] = s[255];
}

__global__ __launch_bounds__(256) void scan_tops_kernel(int* __restrict__ blksum, int nb) {
    __shared__ int s[256];
    int t = threadIdx.x;
    int v = (t < nb) ? blksum[t] : 0;
    s[t] = v;
    __syncthreads();
    #pragma unroll
    for (int d = 1; d < 256; d <<= 1) {
        int add = (t >= d) ? s[t - d] : 0;
        __syncthreads();
        s[t] += add;
        __syncthreads();
    }
    if (t < nb) blksum[t] = s[t] - v;  // exclusive
}

__global__ __launch_bounds__(256) void scan_fix_kernel(const int* __restrict__ counts,
                                                       const int* __restrict__ incl,
                                                       const int* __restrict__ blksum,
                                                       int* __restrict__ off) {
    int i = blockIdx.x * 256 + threadIdx.x;
    if (i < Nn) off[i] = incl[i] - counts[i] + blksum[i >> 8];
}

__global__ __launch_bounds__(256) void fill_csr_kernel(const int* __restrict__ src,
                                                       const int* __restrict__ dst,
                                                       const float* __restrict__ dis,
                                                       const int* __restrict__ off,
                                                       int* __restrict__ cursor,
                                                       int* __restrict__ csr_src,
                                                       float* __restrict__ csr_w) {
    int e = blockIdx.x * 256 + threadIdx.x;
    if (e >= Ee) return;
    int s = src[e], d = dst[e];
    int slot = off[d] + atomicAdd(&cursor[d], 1);
    csr_src[slot] = s;
    csr_w[slot] = dis[s] * dis[d];
}

// ---------------------------------------------------------------------------
// Weight split kernels (fp32 -> bf16 hi/lo, layout B^T [col][K])
// ---------------------------------------------------------------------------
__global__ __launch_bounds__(256) void wsplit_kernel(const float* __restrict__ W,
                                                     unsigned short* __restrict__ bh,
                                                     unsigned short* __restrict__ bl, int n) {
    int i = blockIdx.x * 256 + threadIdx.x;
    if (i >= n) return;
    unsigned short h, l;
    split2(W[i], h, l);
    bh[i] = h;
    bl[i] = l;
}

__global__ __launch_bounds__(256) void wgcnT_kernel(const float* __restrict__ W,
                                                    unsigned short* __restrict__ bh,
                                                    unsigned short* __restrict__ bl) {
    int i = blockIdx.x * 256 + threadIdx.x;
    if (i >= 128 * 128) return;
    int f = i >> 7, hc = i & 127;
    unsigned short h, l;
    split2(W[i], h, l);
    bh[hc * 128 + f] = h;
    bl[hc * 128 + f] = l;
}

// ---------------------------------------------------------------------------
// xw GEMM: xwp[(n*8+t)][128] (fp16) = x_seq[(t*Nn+n)][128] @ W_gcn.
// ---------------------------------------------------------------------------
__global__ __launch_bounds__(256) void xw_gemm(const float* __restrict__ X,
                                               const unsigned short* __restrict__ BTh,
                                               const unsigned short* __restrict__ BTl,
                                               __half* __restrict__ Cout) {
    __shared__ __align__(16) char lds[32768];
    char* pAh = lds;
    char* pAl = lds + 16384;
    const int bm = blockIdx.x * 128;
    const int tid = threadIdx.x;
    const int wid = tid >> 6, lane = tid & 63;
    const int wr = wid >> 1, wc = wid & 1;
    const int l15 = lane & 15, l4 = lane >> 4;

    f32x4 acc[4][4] = {};

    for (int kh = 0; kh < 2; ++kh) {
        if (kh) __syncthreads();
        #pragma unroll
        for (int i = 0; i < 8; ++i) {
            int idx = tid + i * 256;
            int row = idx >> 4;
            int k4 = idx & 15;
            float4 v = *(const float4*)(X + (size_t)(bm + row) * 128 + kh * 64 + k4 * 4);
            ushort4 h, l;
            split2(v.x, h.x, l.x);
            split2(v.y, h.y, l.y);
            split2(v.z, h.z, l.z);
            split2(v.w, h.w, l.w);
            int off = row * 128 + ((k4 * 8) ^ ((row & 7) << 4));
            *(ushort4*)(pAh + off) = h;
            *(ushort4*)(pAl + off) = l;
        }
        __syncthreads();

        #pragma unroll
        for (int kq = 0; kq < 2; ++kq) {
            bf16x8 a_h[4], a_l[4], b_h[4], b_l[4];
            const int kbase = kq * 64 + l4 * 16;
            #pragma unroll
            for (int m = 0; m < 4; ++m) {
                const int r = wr * 64 + m * 16 + l15;
                const int byteo = r * 128 + (kbase ^ ((r & 7) << 4));
                a_h[m] = *(const bf16x8*)(pAh + byteo);
                a_l[m] = *(const bf16x8*)(pAl + byteo);
            }
            #pragma unroll
            for (int n = 0; n < 4; ++n) {
                const int col = wc * 64 + n * 16 + l15;
                const size_t bo = (size_t)col * 128 + kh * 64 + kq * 32 + l4 * 8;
                b_h[n] = *(const bf16x8*)(BTh + bo);
                b_l[n] = *(const bf16x8*)(BTl + bo);
            }
            #pragma unroll
            for (int m = 0; m < 4; ++m)
                #pragma unroll
                for (int n = 0; n < 4; ++n) {
                    acc[m][n] = __builtin_amdgcn_mfma_f32_16x16x32_bf16(a_h[m], b_h[n],
                                                                        acc[m][n], 0, 0, 0);
                    acc[m][n] = __builtin_amdgcn_mfma_f32_16x16x32_bf16(a_h[m], b_l[n],
                                                                        acc[m][n], 0, 0, 0);
                    acc[m][n] = __builtin_amdgcn_mfma_f32_16x16x32_bf16(a_l[m], b_h[n],
                                                                        acc[m][n], 0, 0, 0);
                }
        }
    }

    // epilogue: remap GEMM row r = t*Nn + n  ->  output row n*8 + t (fp16)
    #pragma unroll
    for (int m = 0; m < 4; ++m) {
        const int row = bm + wr * 64 + m * 16 + l4 * 4;
        #pragma unroll
        for (int q = 0; q < 4; ++q) {
            const int r = row + q;
            const int tt = r / Nn;
            const int nn = r - tt * Nn;
            __half* outrow = Cout + ((size_t)nn * 8 + tt) * 128;
            #pragma unroll
            for (int n = 0; n < 4; ++n) {
                const int col = wc * 64 + n * 16 + l15;
                outrow[col] = __float2half(acc[m][n][q]);
            }
        }
    }
}

// ---------------------------------------------------------------------------
// FUSED aggregation + gx GEMM. One block = 8 nodes = 64 rows.
// Phase A: gather xwp 2KB fp16 node-blocks; DEPTH-4 pipeline (2 edges A/B in
//          flight, each prefetching 2 ahead); fp32 accumulate; gcn to LDS.
// Phase B: gx = gcn @ W_ih^T + b_ih -> fp16 [t][n][384], swizzled, plain
//          2-byte stores (measured best: 471us vs nt 584 / LDS-staged 654).
// ---------------------------------------------------------------------------
__global__ __launch_bounds__(256, 1) void aggx_kernel(const __half* __restrict__ xwp,
                                                      const float* __restrict__ dis,
                                                      const int* __restrict__ off,
                                                      const int* __restrict__ counts,
                                                      const int* __restrict__ csr_src,
                                                      const float* __restrict__ csr_w,
                                                      const float* __restrict__ b_gcn,
                                                      const unsigned short* __restrict__ BTh,
                                                      const unsigned short* __restrict__ BTl,
                                                      const float* __restrict__ bias,
                                                      __half* __restrict__ gx16) {
    __shared__ __align__(16) char lds[32768];  // gcn hi 16KB + lo 16KB
    char* pAh = lds;
    char* pAl = lds + 16384;
    const int n0 = blockIdx.x * 8;
    const int tid = threadIdx.x;
    const int wid = tid >> 6, lane = tid & 63;
    const int l15 = lane & 15, l4 = lane >> 4;

    // ---- Phase A: aggregate 2 nodes per wave (fp16 gather, fp32 acc) ----
    for (int nl = 0; nl < 2; ++nl) {
        const int n = n0 + wid * 2 + nl;
        const float dv = dis[n];
        const float dsq = dv * dv;
        float acc0[8], acc1[8];
        {
            const __half* bn_ = xwp + (size_t)n * 1024;
            f16x8 s0v = *(const f16x8*)(bn_ + lane * 8);
            f16x8 s1v = *(const f16x8*)(bn_ + 512 + lane * 8);
            #pragma unroll
            for (int j = 0; j < 8; ++j) {
                acc0[j] = (float)s0v[j] * dsq;
                acc1[j] = (float)s1v[j] * dsq;
            }
        }

        const int s0 = off[n];
        const int cnt = counts[n];
        for (int base = 0; base < cnt; base += 64) {
            const int m = min(64, cnt - base);
            int idxv = 0;
            float wvv = 0.f;
            {
                int j = base + lane;
                if (j < cnt) {
                    idxv = csr_src[s0 + j];
                    wvv = csr_w[s0 + j];
                }
            }
            // depth-4 pipeline: edges A (even) and B (odd), each prefetch +2
            int sA = __shfl(idxv, 0);
            float wA = __shfl(wvv, 0);
            const __half* pA = xwp + (size_t)sA * 1024;
            f16x8 a0 = *(const f16x8*)(pA + lane * 8);
            f16x8 a1 = *(const f16x8*)(pA + 512 + lane * 8);
            f16x8 b0 = a0, b1 = a1;
            float wB = 0.f;
            if (1 < m) {
                int sB = __shfl(idxv, 1);
                wB = __shfl(wvv, 1);
                const __half* pB = xwp + (size_t)sB * 1024;
                b0 = *(const f16x8*)(pB + lane * 8);
                b1 = *(const f16x8*)(pB + 512 + lane * 8);
            }
            for (int k = 0; k < m; k += 2) {
                f16x8 ua0 = a0, ua1 = a1;
                const float uwa = wA;
                if (k + 2 < m) {
                    int sN = __shfl(idxv, k + 2);
                    wA = __shfl(wvv, k + 2);
                    const __half* pN = xwp + (size_t)sN * 1024;
                    a0 = *(const f16x8*)(pN + lane * 8);
                    a1 = *(const f16x8*)(pN + 512 + lane * 8);
                }
                #pragma unroll
                for (int j = 0; j < 8; ++j) {
                    acc0[j] = fmaf((float)ua0[j], uwa, acc0[j]);
                    acc1[j] = fmaf((float)ua1[j], uwa, acc1[j]);
                }
                if (k + 1 < m) {
                    f16x8 ub0 = b0, ub1 = b1;
                    const float uwb = wB;
                    if (k + 3 < m) {
                        int sN = __shfl(idxv, k + 3);
                        wB = __shfl(wvv, k + 3);
                        const __half* pN = xwp + (size_t)sN * 1024;
                        b0 = *(const f16x8*)(pN + lane * 8);
                        b1 = *(const f16x8*)(pN + 512 + lane * 8);
                    }
                    #pragma unroll
                    for (int j = 0; j < 8; ++j) {
                        acc0[j] = fmaf((float)ub0[j], uwb, acc0[j]);
                        acc1[j] = fmaf((float)ub1[j], uwb, acc1[j]);
                    }
                }
            }
        }

        // relu + bias, split, write into LDS (swizzled). chunk p covers
        // t = p*4 + (lane>>4), cols c0..c0+7 with c0 = (lane&15)*8.
        #pragma unroll
        for (int p = 0; p < 2; ++p) {
            const int t = p * 4 + l4;
            const int c0 = l15 * 8;
            float4 bbA = *(const float4*)(b_gcn + c0);
            float4 bbB = *(const float4*)(b_gcn + c0 + 4);
            const float* ap = p ? acc1 : acc0;
            float v[8];
            v[0] = fmaxf(ap[0] + bbA.x, 0.f);
            v[1] = fmaxf(ap[1] + bbA.y, 0.f);
            v[2] = fmaxf(ap[2] + bbA.z, 0.f);
            v[3] = fmaxf(ap[3] + bbA.w, 0.f);
            v[4] = fmaxf(ap[4] + bbB.x, 0.f);
            v[5] = fmaxf(ap[5] + bbB.y, 0.f);
            v[6] = fmaxf(ap[6] + bbB.z, 0.f);
            v[7] = fmaxf(ap[7] + bbB.w, 0.f);
            ushort4 oh0, ol0, oh1, ol1;
            split2(v[0], oh0.x, ol0.x);
            split2(v[1], oh0.y, ol0.y);
            split2(v[2], oh0.z, ol0.z);
            split2(v[3], oh0.w, ol0.w);
            split2(v[4], oh1.x, ol1.x);
            split2(v[5], oh1.y, ol1.y);
            split2(v[6], oh1.z, ol1.z);
            split2(v[7], oh1.w, ol1.w);
            const int r = (wid * 2 + nl) * 8 + t;        // local row, r&7 == t
            const int o1 = r * 256 + ((c0 * 2) ^ (t << 4));
            *(ushort4*)(pAh + o1) = oh0;
            *(ushort4*)(pAh + o1 + 8) = oh1;
            *(ushort4*)(pAl + o1) = ol0;
            *(ushort4*)(pAl + o1 + 8) = ol1;
        }
    }
    __syncthreads();

    // ---- Phase B: gx = gcn @ W_ih^T + b_ih, wave owns 96 cols ----
    f32x4 acc[4][6] = {};
    const int wc0 = wid * 96;
    #pragma unroll
    for (int kq = 0; kq < 4; ++kq) {
        bf16x8 a_h[4], a_l[4];
        const int kbase = kq * 64 + l4 * 16;
        #pragma unroll
        for (int m = 0; m < 4; ++m) {
            const int r = m * 16 + l15;
            const int byteo = r * 256 + (kbase ^ ((r & 7) << 4));
            a_h[m] = *(const bf16x8*)(pAh + byteo);
            a_l[m] = *(const bf16x8*)(pAl + byteo);
        }
        #pragma unroll
        for (int n = 0; n < 6; ++n) {
            const int col = wc0 + n * 16 + l15;
            const size_t bo = (size_t)col * 128 + kq * 32 + l4 * 8;
            bf16x8 b_h = *(const bf16x8*)(BTh + bo);
            bf16x8 b_l = *(const bf16x8*)(BTl + bo);
            #pragma unroll
            for (int m = 0; m < 4; ++m) {
                acc[m][n] = __builtin_amdgcn_mfma_f32_16x16x32_bf16(a_h[m], b_h,
                                                                    acc[m][n], 0, 0, 0);
                acc[m][n] = __builtin_amdgcn_mfma_f32_16x16x32_bf16(a_h[m], b_l,
                                                                    acc[m][n], 0, 0, 0);
                acc[m][n] = __builtin_amdgcn_mfma_f32_16x16x32_bf16(a_l[m], b_h,
                                                                    acc[m][n], 0, 0, 0);
            }
        }
    }

    // epilogue: local row lr = node_local*8 + t  ->  gx row t*Nn + node,
    // intra-row byte XOR-swizzled by (node&7)<<4; plain 2-byte stores
    #pragma unroll
    for (int n = 0; n < 6; ++n) {
        const int col = wc0 + n * 16 + l15;
        const float bb = bias[col];
        #pragma unroll
        for (int m = 0; m < 4; ++m) {
            #pragma unroll
            for (int q = 0; q < 4; ++q) {
                const int lr = m * 16 + l4 * 4 + q;
                const int tt = lr & 7;
                const int node = n0 + (lr >> 3);
                const size_t rowb = ((size_t)tt * Nn + node) * 768;
                const int cb = (col * 2) ^ ((node & 7) << 4);
                *(__half*)((char*)gx16 + rowb + cb) = __float2half(acc[m][n][q] + bb);
            }
        }
    }
}

// ---------------------------------------------------------------------------
// GRU v7: block = 64 nodes, 4 waves, register-local gate, h state in LDS,
// two node-groups per step; launch_bounds(256,1) -> no VGPR spills.
// ---------------------------------------------------------------------------
__global__ __launch_bounds__(256, 1) void gru_kernel(const unsigned short* __restrict__ BTh,
                                                     const unsigned short* __restrict__ BTl,
                                                     const __half* __restrict__ gx,
                                                     const float* __restrict__ b_hh,
                                                     float* __restrict__ hbuf) {
    __shared__ __align__(16) char lds[81920];  // hHi 16K | hLo 16K | gxS 48K
    char* pHh = lds;
    char* pHl = lds + 16384;
    char* gxS = lds + 32768;
    const int tid = threadIdx.x;
    const int wid = tid >> 6, lane = tid & 63;
    const int l15 = lane & 15, l4 = lane >> 4;
    const int n0 = blockIdx.x * 64;

    float bh[3][2];
    #pragma unroll
    for (int g = 0; g < 3; ++g)
        #pragma unroll
        for (int tt = 0; tt < 2; ++tt)
            bh[g][tt] = b_hh[g * 128 + wid * 32 + tt * 16 + l15];

    #define ISSUE_GX(T)                                                                  \
        {                                                                                \
            const char* srcb = (const char*)(gx + ((size_t)(T) * Nn + n0) * 384);        \
            _Pragma("unroll")                                                            \
            for (int i = 0; i < 12; ++i) {                                               \
                const int o = i * 4096 + tid * 16;                                       \
                __builtin_amdgcn_global_load_lds(                                        \
                    (const __attribute__((address_space(1))) void*)(srcb + o),           \
                    (__attribute__((address_space(3))) void*)(gxS + o), 16, 0, 0);       \
            }                                                                            \
        }

    // ---- t = 0: gh = 0 (h=0); write h(0) to LDS only ----
    ISSUE_GX(0);
    __syncthreads();
    #pragma unroll
    for (int m = 0; m < 4; ++m) {
        #pragma unroll
        for (int q = 0; q < 4; ++q) {
            const int nl = m * 16 + l4 * 4 + q;
            const char* rp = gxS + nl * 768;
            const int key = (nl & 7) << 4;
            #pragma unroll
            for (int tt = 0; tt < 2; ++tt) {
                const int c0 = wid * 32 + tt * 16 + l15;
                float xr = __half2float(*(const __half*)(rp + ((2 * c0) ^ key)));
                float xz = __half2float(*(const __half*)(rp + ((2 * (c0 + 128)) ^ key)));
                float xn = __half2float(*(const __half*)(rp + ((2 * (c0 + 256)) ^ key)));
                float rg = 1.f / (1.f + expf(-(xr + bh[0][tt])));
                float zg = 1.f / (1.f + expf(-(xz + bh[1][tt])));
                float ng = tanhf(xn + rg * bh[2][tt]);
                float hnew = (1.f - zg) * ng;
                unsigned short sh, sl;
                split2(hnew, sh, sl);
                const int byteo = nl * 256 + ((2 * c0) ^ key);
                *(unsigned short*)(pHh + byteo) = sh;
                *(unsigned short*)(pHl + byteo) = sl;
            }
        }
    }

    for (int t = 1; t < Tt; ++t) {
        __syncthreads();  // gates of t-1 done (gxS reads retired, h(t-1) complete)
        ISSUE_GX(t);      // async: lands during group-0 MFMA

        const int wlast = (t == Tt - 1);
        #pragma unroll
        for (int grp = 0; grp < 2; ++grp) {
            f32x4 acc[2][6];
            #pragma unroll
            for (int m = 0; m < 2; ++m)
                #pragma unroll
                for (int j = 0; j < 6; ++j) acc[m][j] = (f32x4){0.f, 0.f, 0.f, 0.f};
            const int akey = (l15 & 7) << 4;
            #pragma unroll
            for (int kq = 0; kq < 4; ++kq) {
                bf16x8 a_h[2], a_l[2];
                #pragma unroll
                for (int m = 0; m < 2; ++m) {
                    const int ab = ((grp * 2 + m) * 16 + l15) * 256 +
                                   ((kq * 64 + l4 * 16) ^ akey);
                    a_h[m] = *(const bf16x8*)(pHh + ab);
                    a_l[m] = *(const bf16x8*)(pHl + ab);
                }
                #pragma unroll
                for (int j = 0; j < 6; ++j) {
                    const int g = j >> 1, tt = j & 1;
                    const int col = g * 128 + wid * 32 + tt * 16 + l15;
                    const size_t bo = (size_t)col * 128 + kq * 32 + l4 * 8;
                    bf16x8 b_h = *(const bf16x8*)(BTh + bo);
                    bf16x8 b_l = *(const bf16x8*)(BTl + bo);
                    #pragma unroll
                    for (int m = 0; m < 2; ++m) {
                        acc[m][j] = __builtin_amdgcn_mfma_f32_16x16x32_bf16(a_h[m], b_h,
                                                                           acc[m][j], 0, 0, 0);
                        acc[m][j] = __builtin_amdgcn_mfma_f32_16x16x32_bf16(a_h[m], b_l,
                                                                           acc[m][j], 0, 0, 0);
                        acc[m][j] = __builtin_amdgcn_mfma_f32_16x16x32_bf16(a_l[m], b_h,
                                                                           acc[m][j], 0, 0, 0);
                    }
                }
            }
            __syncthreads();  // group's MFMA h-reads done; (grp 0) gx landed

            #pragma unroll
            for (int m = 0; m < 2; ++m) {
                #pragma unroll
                for (int q = 0; q < 4; ++q) {
                    const int nl = (grp * 2 + m) * 16 + l4 * 4 + q;
                    const char* rp = gxS + nl * 768;
                    const int key = (nl & 7) << 4;
                    #pragma unroll
                    for (int tt = 0; tt < 2; ++tt) {
                        const int c0 = wid * 32 + tt * 16 + l15;
                        const int byteo = nl * 256 + ((2 * c0) ^ key);
                        float xr = __half2float(*(const __half*)(rp + ((2 * c0) ^ key)));
                        float xz = __half2float(*(const __half*)(rp + ((2 * (c0 + 128)) ^ key)));
                        float xn = __half2float(*(const __half*)(rp + ((2 * (c0 + 256)) ^ key)));
                        float h_old = bf2f(*(const unsigned short*)(pHh + byteo)) +
                                      bf2f(*(const unsigned short*)(pHl + byteo));
                        float ghr = acc[m][0 + tt][q] + bh[0][tt];
                        float ghz = acc[m][2 + tt][q] + bh[1][tt];
                        float ghn = acc[m][4 + tt][q] + bh[2][tt];
                        float rg = 1.f / (1.f + expf(-(xr + ghr)));
                        float zg = 1.f / (1.f + expf(-(xz + ghz)));
                        float ng = tanhf(xn + rg * ghn);
                        float hnew = (1.f - zg) * ng + zg * h_old;
                        if (!wlast) {
                            unsigned short sh, sl;
                            split2(hnew, sh, sl);
                            *(unsigned short*)(pHh + byteo) = sh;
                            *(unsigned short*)(pHl + byteo) = sl;
                        } else {
                            const int row = n0 + nl;
                            if (row < Nn) hbuf[(size_t)row * 128 + c0] = hnew;
                        }
                    }
                }
            }
        }
    }
    #undef ISSUE_GX
}

// ---------------------------------------------------------------------------
// Graph sizes by binary search on the SORTED batch array
// ---------------------------------------------------------------------------
__global__ void gcount_bs_kernel(const int* __restrict__ batch, float* __restrict__ ginv) {
    int g = threadIdx.x;
    if (g >= Gg) return;
    int lo = 0, hi = Nn;
    while (lo < hi) {
        int m = (lo + hi) >> 1;
        if (batch[m] < g) lo = m + 1; else hi = m;
    }
    int start = lo;
    lo = 0; hi = Nn;
    while (lo < hi) {
        int m = (lo + hi) >> 1;
        if (batch[m] <= g) lo = m + 1; else hi = m;
    }
    ginv[g] = 1.f / fmaxf((float)(lo - start), 1.f);
}

// ---------------------------------------------------------------------------
// FC (h @ W_fc + b_fc) fused with mean pooling via atomics
// ---------------------------------------------------------------------------
__global__ __launch_bounds__(256) void fc_pool_kernel(const float* __restrict__ h,
                                                      const float* __restrict__ Wfc,
                                                      const float* __restrict__ bfc,
                                                      const int* __restrict__ batch,
                                                      const float* __restrict__ ginv,
                                                      float* __restrict__ out) {
    __shared__ float hs[16][128];
    __shared__ float wf[128][10];
    __shared__ float bf[10];
    int b0 = blockIdx.x * 16;
    int t = threadIdx.x;
    for (int i = t; i < 128 * 10; i += 256) wf[i / 10][i % 10] = Wfc[i];
    if (t < 10) bf[t] = bfc[t];
    for (int i = t; i < 16 * 32; i += 256) {
        int r = i >> 5, c4 = i & 31;
        int row = b0 + r;
        float4 v = make_float4(0.f, 0.f, 0.f, 0.f);
        if (row < Nn) v = *(const float4*)(h + (size_t)row * 128 + c4 * 4);
        *(float4*)(&hs[r][c4 * 4]) = v;
    }
    __syncthreads();
    if (t < 160) {
        int r = t / 10, c = t % 10;
        int row = b0 + r;
        if (row < Nn) {
            float acc = bf[c];
            #pragma unroll
            for (int k = 0; k < 128; ++k) acc = fmaf(hs[r][k], wf[k][c], acc);
            int g = batch[row];
            atomicAdd(out + g * 10 + c, acc * ginv[g]);
        }
    }
}

// ---------------------------------------------------------------------------
// Launch
// ---------------------------------------------------------------------------
extern "C" void kernel_launch(void* const* d_in, const int* in_sizes, int n_in,
                              void* d_out, int out_size, void* d_ws, size_t ws_size,
                              hipStream_t stream) {
    const float* x_seq = (const float*)d_in[0];
    const int*   eidx  = (const int*)d_in[1];
    const int*   batch = (const int*)d_in[2];
    const float* W_gcn = (const float*)d_in[3];
    const float* b_gcn = (const float*)d_in[4];
    const float* W_ih  = (const float*)d_in[5];
    const float* W_hh  = (const float*)d_in[6];
    const float* b_ih  = (const float*)d_in[7];
    const float* b_hh  = (const float*)d_in[8];
    const float* W_fc  = (const float*)d_in[9];
    const float* b_fc  = (const float*)d_in[10];
    const int* src = eidx;
    const int* dst = eidx + Ee;
    float* out = (float*)d_out;

    size_t woff = 0;
    auto alloc = [&](size_t bytes) -> void* {
        void* p = (char*)d_ws + woff;
        woff = (woff + bytes + 255) & ~(size_t)255;
        return p;
    };
    int*   counts  = (int*)alloc(Nn * 4);
    int*   cursor  = (int*)alloc(Nn * 4);
    int*   incl    = (int*)alloc(Nn * 4);
    int*   blksum  = (int*)alloc(256 * 4);
    int*   offx    = (int*)alloc(Nn * 4);
    int*   csr_src = (int*)alloc(Ee * 4);
    float* csr_w   = (float*)alloc(Ee * 4);
    float* dis     = (float*)alloc(Nn * 4);
    unsigned short* wg_hi  = (unsigned short*)alloc(128 * 128 * 2);
    unsigned short* wg_lo  = (unsigned short*)alloc(128 * 128 * 2);
    unsigned short* wih_hi = (unsigned short*)alloc(384 * 128 * 2);
    unsigned short* wih_lo = (unsigned short*)alloc(384 * 128 * 2);
    unsigned short* whh_hi = (unsigned short*)alloc(384 * 128 * 2);
    unsigned short* whh_lo = (unsigned short*)alloc(384 * 128 * 2);
    float* ginv = (float*)alloc(256);
    __half* xwp  = (__half*)alloc((size_t)NT * 128 * 2);  // 102.4 MB fp16, [n][t][128]
    __half* gx16 = (__half*)alloc((size_t)NT * 384 * 2);  // 307.2 MB, [t][n][384] swz
    float* hbuf  = (float*)alloc((size_t)Nn * 128 * 4);   // 25.6 MB (also DMA tail pad)

    hipMemsetAsync(counts, 0, Nn * 4, stream);
    hipMemsetAsync(cursor, 0, Nn * 4, stream);
    hipMemsetAsync(d_out, 0, (size_t)Gg * Cc * 4, stream);

    const int nbN = (Nn + 255) / 256;
    const int nbE = (Ee + 255) / 256;

    count_deg_kernel<<<nbE, 256, 0, stream>>>(dst, counts);
    dis_kernel<<<nbN, 256, 0, stream>>>(counts, dis);
    scan_block_kernel<<<nbN, 256, 0, stream>>>(counts, incl, blksum);
    scan_tops_kernel<<<1, 256, 0, stream>>>(blksum, nbN);
    scan_fix_kernel<<<nbN, 256, 0, stream>>>(counts, incl, blksum, offx);
    fill_csr_kernel<<<nbE, 256, 0, stream>>>(src, dst, dis, offx, cursor, csr_src, csr_w);

    wsplit_kernel<<<(384 * 128 + 255) / 256, 256, 0, stream>>>(W_ih, wih_hi, wih_lo, 384 * 128);
    wsplit_kernel<<<(384 * 128 + 255) / 256, 256, 0, stream>>>(W_hh, whh_hi, whh_lo, 384 * 128);
    wgcnT_kernel<<<(128 * 128 + 255) / 256, 256, 0, stream>>>(W_gcn, wg_hi, wg_lo);
    gcount_bs_kernel<<<1, 64, 0, stream>>>(batch, ginv);

    // xw for all T, output [n][t][128] fp16 (L3-resident gather source)
    xw_gemm<<<NT / 128, 256, 0, stream>>>(x_seq, wg_hi, wg_lo, xwp);
    // fused aggregation + gx GEMM (round-15 best config)
    aggx_kernel<<<Nn / 8, 256, 0, stream>>>(xwp, dis, offx, counts, csr_src, csr_w,
                                            b_gcn, wih_hi, wih_lo, b_ih, gx16);
    // GRU v7
    gru_kernel<<<(Nn + 63) / 64, 256, 0, stream>>>(whh_hi, whh_lo, gx16, b_hh, hbuf);

    fc_pool_kernel<<<(Nn + 15) / 16, 256, 0, stream>>>(hbuf, W_fc, b_fc, batch, ginv, out);
}

// Round 20
// 1100.146 us; speedup vs baseline: 1.2116x; 1.0460x over previous
//
#include <hip/hip_runtime.h>
#include <hip/hip_bf16.h>
#include <hip/hip_fp16.h>
#include <cstddef>
#include <cstdint>

// Problem constants (from reference)
#define Nn 50000
#define Ee 800000
#define Tt 8
#define Ff 128
#define Hh 128
#define Cc 10
#define Gg 64
#define NT 400000    // Tt * Nn

typedef __attribute__((ext_vector_type(8))) short bf16x8;
typedef __attribute__((ext_vector_type(4))) float f32x4;
typedef __attribute__((ext_vector_type(8))) _Float16 f16x8;

__device__ inline unsigned short f2bf(float x) {
    __hip_bfloat16 b = __float2bfloat16(x);
    return *reinterpret_cast<unsigned short*>(&b);
}
__device__ inline float bf2f(unsigned short u) {
    __hip_bfloat16 b = *reinterpret_cast<__hip_bfloat16*>(&u);
    return __bfloat162float(b);
}
__device__ inline void split2(float x, unsigned short& h, unsigned short& l) {
    h = f2bf(x);
    l = f2bf(x - bf2f(h));
}

// ---------------------------------------------------------------------------
// Degree / normalization / CSR build
// ---------------------------------------------------------------------------
__global__ __launch_bounds__(256) void count_deg_kernel(const int* __restrict__ dst,
                                                        int* __restrict__ counts) {
    int e = blockIdx.x * 256 + threadIdx.x;
    if (e < Ee) atomicAdd(&counts[dst[e]], 1);
}

__global__ __launch_bounds__(256) void dis_kernel(const int* __restrict__ counts,
                                                  float* __restrict__ dis) {
    int i = blockIdx.x * 256 + threadIdx.x;
    if (i < Nn) dis[i] = 1.0f / sqrtf((float)counts[i] + 1.0f);
}

__global__ __launch_bounds__(256) void scan_block_kernel(const int* __restrict__ counts,
                                                         int* __restrict__ incl,
                                                         int* __restrict__ blksum) {
    __shared__ int s[256];
    int t = threadIdx.x;
    int i = blockIdx.x * 256 + t;
    int v = (i < Nn) ? counts[i] : 0;
    s[t] = v;
    __syncthreads();
    #pragma unroll
    for (int d = 1; d < 256; d <<= 1) {
        int add = (t >= d) ? s[t - d] : 0;
        __syncthreads();
        s[t] += add;
        __syncthreads();
    }
    if (i < Nn) incl[i] = s[t];
    if (t == 255) blksum[blockIdx.x] = s[255];
}

__global__ __launch_bounds__(256) void scan_tops_kernel(int* __restrict__ blksum, int nb) {
    __shared__ int s[256];
    int t = threadIdx.x;
    int v = (t < nb) ? blksum[t] : 0;
    s[t] = v;
    __syncthreads();
    #pragma unroll
    for (int d = 1; d < 256; d <<= 1) {
        int add = (t >= d) ? s[t - d] : 0;
        __syncthreads();
        s[t] += add;
        __syncthreads();
    }
    if (t < nb) blksum[t] = s[t] - v;  // exclusive
}

__global__ __launch_bounds__(256) void scan_fix_kernel(const int* __restrict__ counts,
                                                       const int* __restrict__ incl,
                                                       const int* __restrict__ blksum,
                                                       int* __restrict__ off) {
    int i = blockIdx.x * 256 + threadIdx.x;
    if (i < Nn) off[i] = incl[i] - counts[i] + blksum[i >> 8];
}

__global__ __launch_bounds__(256) void fill_csr_kernel(const int* __restrict__ src,
                                                       const int* __restrict__ dst,
                                                       const float* __restrict__ dis,
                                                       const int* __restrict__ off,
                                                       int* __restrict__ cursor,
                                                       int* __restrict__ csr_src,
                                                       float* __restrict__ csr_w) {
    int e = blockIdx.x * 256 + threadIdx.x;
    if (e >= Ee) return;
    int s = src[e], d = dst[e];
    int slot = off[d] + atomicAdd(&cursor[d], 1);
    csr_src[slot] = s;
    csr_w[slot] = dis[s] * dis[d];
}

// ---------------------------------------------------------------------------
// Weight split kernels (fp32 -> bf16 hi/lo, layout B^T [col][K])
// ---------------------------------------------------------------------------
__global__ __launch_bounds__(256) void wsplit_kernel(const float* __restrict__ W,
                                                     unsigned short* __restrict__ bh,
                                                     unsigned short* __restrict__ bl, int n) {
    int i = blockIdx.x * 256 + threadIdx.x;
    if (i >= n) return;
    unsigned short h, l;
    split2(W[i], h, l);
    bh[i] = h;
    bl[i] = l;
}

__global__ __launch_bounds__(256) void wgcnT_kernel(const float* __restrict__ W,
                                                    unsigned short* __restrict__ bh,
                                                    unsigned short* __restrict__ bl) {
    int i = blockIdx.x * 256 + threadIdx.x;
    if (i >= 128 * 128) return;
    int f = i >> 7, hc = i & 127;
    unsigned short h, l;
    split2(W[i], h, l);
    bh[hc * 128 + f] = h;
    bl[hc * 128 + f] = l;
}

// ---------------------------------------------------------------------------
// xw GEMM: xwp[(n*8+t)][128] (fp16) = x_seq[(t*Nn+n)][128] @ W_gcn.
// ---------------------------------------------------------------------------
__global__ __launch_bounds__(256) void xw_gemm(const float* __restrict__ X,
                                               const unsigned short* __restrict__ BTh,
                                               const unsigned short* __restrict__ BTl,
                                               __half* __restrict__ Cout) {
    __shared__ __align__(16) char lds[32768];
    char* pAh = lds;
    char* pAl = lds + 16384;
    const int bm = blockIdx.x * 128;
    const int tid = threadIdx.x;
    const int wid = tid >> 6, lane = tid & 63;
    const int wr = wid >> 1, wc = wid & 1;
    const int l15 = lane & 15, l4 = lane >> 4;

    f32x4 acc[4][4] = {};

    for (int kh = 0; kh < 2; ++kh) {
        if (kh) __syncthreads();
        #pragma unroll
        for (int i = 0; i < 8; ++i) {
            int idx = tid + i * 256;
            int row = idx >> 4;
            int k4 = idx & 15;
            float4 v = *(const float4*)(X + (size_t)(bm + row) * 128 + kh * 64 + k4 * 4);
            ushort4 h, l;
            split2(v.x, h.x, l.x);
            split2(v.y, h.y, l.y);
            split2(v.z, h.z, l.z);
            split2(v.w, h.w, l.w);
            int off = row * 128 + ((k4 * 8) ^ ((row & 7) << 4));
            *(ushort4*)(pAh + off) = h;
            *(ushort4*)(pAl + off) = l;
        }
        __syncthreads();

        #pragma unroll
        for (int kq = 0; kq < 2; ++kq) {
            bf16x8 a_h[4], a_l[4], b_h[4], b_l[4];
            const int kbase = kq * 64 + l4 * 16;
            #pragma unroll
            for (int m = 0; m < 4; ++m) {
                const int r = wr * 64 + m * 16 + l15;
                const int byteo = r * 128 + (kbase ^ ((r & 7) << 4));
                a_h[m] = *(const bf16x8*)(pAh + byteo);
                a_l[m] = *(const bf16x8*)(pAl + byteo);
            }
            #pragma unroll
            for (int n = 0; n < 4; ++n) {
                const int col = wc * 64 + n * 16 + l15;
                const size_t bo = (size_t)col * 128 + kh * 64 + kq * 32 + l4 * 8;
                b_h[n] = *(const bf16x8*)(BTh + bo);
                b_l[n] = *(const bf16x8*)(BTl + bo);
            }
            #pragma unroll
            for (int m = 0; m < 4; ++m)
                #pragma unroll
                for (int n = 0; n < 4; ++n) {
                    acc[m][n] = __builtin_amdgcn_mfma_f32_16x16x32_bf16(a_h[m], b_h[n],
                                                                        acc[m][n], 0, 0, 0);
                    acc[m][n] = __builtin_amdgcn_mfma_f32_16x16x32_bf16(a_h[m], b_l[n],
                                                                        acc[m][n], 0, 0, 0);
                    acc[m][n] = __builtin_amdgcn_mfma_f32_16x16x32_bf16(a_l[m], b_h[n],
                                                                        acc[m][n], 0, 0, 0);
                }
        }
    }

    // epilogue: remap GEMM row r = t*Nn + n  ->  output row n*8 + t (fp16)
    #pragma unroll
    for (int m = 0; m < 4; ++m) {
        const int row = bm + wr * 64 + m * 16 + l4 * 4;
        #pragma unroll
        for (int q = 0; q < 4; ++q) {
            const int r = row + q;
            const int tt = r / Nn;
            const int nn = r - tt * Nn;
            __half* outrow = Cout + ((size_t)nn * 8 + tt) * 128;
            #pragma unroll
            for (int n = 0; n < 4; ++n) {
                const int col = wc * 64 + n * 16 + l15;
                outrow[col] = __float2half(acc[m][n][q]);
            }
        }
    }
}

// ---------------------------------------------------------------------------
// FUSED aggregation + gx GEMM. One block = 8 nodes = 64 rows.
// Phase A: gather xwp 2KB fp16 node-blocks; DEPTH-4 pipeline; fp32 acc.
// Phase B: gx = gcn @ W_ih^T + b_ih -> fp16 [t][n][384], swizzled, plain
//          2-byte stores (measured best: 460us).
// ---------------------------------------------------------------------------
__global__ __launch_bounds__(256, 1) void aggx_kernel(const __half* __restrict__ xwp,
                                                      const float* __restrict__ dis,
                                                      const int* __restrict__ off,
                                                      const int* __restrict__ counts,
                                                      const int* __restrict__ csr_src,
                                                      const float* __restrict__ csr_w,
                                                      const float* __restrict__ b_gcn,
                                                      const unsigned short* __restrict__ BTh,
                                                      const unsigned short* __restrict__ BTl,
                                                      const float* __restrict__ bias,
                                                      __half* __restrict__ gx16) {
    __shared__ __align__(16) char lds[32768];  // gcn hi 16KB + lo 16KB
    char* pAh = lds;
    char* pAl = lds + 16384;
    const int n0 = blockIdx.x * 8;
    const int tid = threadIdx.x;
    const int wid = tid >> 6, lane = tid & 63;
    const int l15 = lane & 15, l4 = lane >> 4;

    // ---- Phase A: aggregate 2 nodes per wave (fp16 gather, fp32 acc) ----
    for (int nl = 0; nl < 2; ++nl) {
        const int n = n0 + wid * 2 + nl;
        const float dv = dis[n];
        const float dsq = dv * dv;
        float acc0[8], acc1[8];
        {
            const __half* bn_ = xwp + (size_t)n * 1024;
            f16x8 s0v = *(const f16x8*)(bn_ + lane * 8);
            f16x8 s1v = *(const f16x8*)(bn_ + 512 + lane * 8);
            #pragma unroll
            for (int j = 0; j < 8; ++j) {
                acc0[j] = (float)s0v[j] * dsq;
                acc1[j] = (float)s1v[j] * dsq;
            }
        }

        const int s0 = off[n];
        const int cnt = counts[n];
        for (int base = 0; base < cnt; base += 64) {
            const int m = min(64, cnt - base);
            int idxv = 0;
            float wvv = 0.f;
            {
                int j = base + lane;
                if (j < cnt) {
                    idxv = csr_src[s0 + j];
                    wvv = csr_w[s0 + j];
                }
            }
            // depth-4 pipeline: edges A (even) and B (odd), each prefetch +2
            int sA = __shfl(idxv, 0);
            float wA = __shfl(wvv, 0);
            const __half* pA = xwp + (size_t)sA * 1024;
            f16x8 a0 = *(const f16x8*)(pA + lane * 8);
            f16x8 a1 = *(const f16x8*)(pA + 512 + lane * 8);
            f16x8 b0 = a0, b1 = a1;
            float wB = 0.f;
            if (1 < m) {
                int sB = __shfl(idxv, 1);
                wB = __shfl(wvv, 1);
                const __half* pB = xwp + (size_t)sB * 1024;
                b0 = *(const f16x8*)(pB + lane * 8);
                b1 = *(const f16x8*)(pB + 512 + lane * 8);
            }
            for (int k = 0; k < m; k += 2) {
                f16x8 ua0 = a0, ua1 = a1;
                const float uwa = wA;
                if (k + 2 < m) {
                    int sN = __shfl(idxv, k + 2);
                    wA = __shfl(wvv, k + 2);
                    const __half* pN = xwp + (size_t)sN * 1024;
                    a0 = *(const f16x8*)(pN + lane * 8);
                    a1 = *(const f16x8*)(pN + 512 + lane * 8);
                }
                #pragma unroll
                for (int j = 0; j < 8; ++j) {
                    acc0[j] = fmaf((float)ua0[j], uwa, acc0[j]);
                    acc1[j] = fmaf((float)ua1[j], uwa, acc1[j]);
                }
                if (k + 1 < m) {
                    f16x8 ub0 = b0, ub1 = b1;
                    const float uwb = wB;
                    if (k + 3 < m) {
                        int sN = __shfl(idxv, k + 3);
                        wB = __shfl(wvv, k + 3);
                        const __half* pN = xwp + (size_t)sN * 1024;
                        b0 = *(const f16x8*)(pN + lane * 8);
                        b1 = *(const f16x8*)(pN + 512 + lane * 8);
                    }
                    #pragma unroll
                    for (int j = 0; j < 8; ++j) {
                        acc0[j] = fmaf((float)ub0[j], uwb, acc0[j]);
                        acc1[j] = fmaf((float)ub1[j], uwb, acc1[j]);
                    }
                }
            }
        }

        // relu + bias, split, write into LDS (swizzled). chunk p covers
        // t = p*4 + (lane>>4), cols c0..c0+7 with c0 = (lane&15)*8.
        #pragma unroll
        for (int p = 0; p < 2; ++p) {
            const int t = p * 4 + l4;
            const int c0 = l15 * 8;
            float4 bbA = *(const float4*)(b_gcn + c0);
            float4 bbB = *(const float4*)(b_gcn + c0 + 4);
            const float* ap = p ? acc1 : acc0;
            float v[8];
            v[0] = fmaxf(ap[0] + bbA.x, 0.f);
            v[1] = fmaxf(ap[1] + bbA.y, 0.f);
            v[2] = fmaxf(ap[2] + bbA.z, 0.f);
            v[3] = fmaxf(ap[3] + bbA.w, 0.f);
            v[4] = fmaxf(ap[4] + bbB.x, 0.f);
            v[5] = fmaxf(ap[5] + bbB.y, 0.f);
            v[6] = fmaxf(ap[6] + bbB.z, 0.f);
            v[7] = fmaxf(ap[7] + bbB.w, 0.f);
            ushort4 oh0, ol0, oh1, ol1;
            split2(v[0], oh0.x, ol0.x);
            split2(v[1], oh0.y, ol0.y);
            split2(v[2], oh0.z, ol0.z);
            split2(v[3], oh0.w, ol0.w);
            split2(v[4], oh1.x, ol1.x);
            split2(v[5], oh1.y, ol1.y);
            split2(v[6], oh1.z, ol1.z);
            split2(v[7], oh1.w, ol1.w);
            const int r = (wid * 2 + nl) * 8 + t;        // local row, r&7 == t
            const int o1 = r * 256 + ((c0 * 2) ^ (t << 4));
            *(ushort4*)(pAh + o1) = oh0;
            *(ushort4*)(pAh + o1 + 8) = oh1;
            *(ushort4*)(pAl + o1) = ol0;
            *(ushort4*)(pAl + o1 + 8) = ol1;
        }
    }
    __syncthreads();

    // ---- Phase B: gx = gcn @ W_ih^T + b_ih, wave owns 96 cols ----
    f32x4 acc[4][6] = {};
    const int wc0 = wid * 96;
    #pragma unroll
    for (int kq = 0; kq < 4; ++kq) {
        bf16x8 a_h[4], a_l[4];
        const int kbase = kq * 64 + l4 * 16;
        #pragma unroll
        for (int m = 0; m < 4; ++m) {
            const int r = m * 16 + l15;
            const int byteo = r * 256 + (kbase ^ ((r & 7) << 4));
            a_h[m] = *(const bf16x8*)(pAh + byteo);
            a_l[m] = *(const bf16x8*)(pAl + byteo);
        }
        #pragma unroll
        for (int n = 0; n < 6; ++n) {
            const int col = wc0 + n * 16 + l15;
            const size_t bo = (size_t)col * 128 + kq * 32 + l4 * 8;
            bf16x8 b_h = *(const bf16x8*)(BTh + bo);
            bf16x8 b_l = *(const bf16x8*)(BTl + bo);
            #pragma unroll
            for (int m = 0; m < 4; ++m) {
                acc[m][n] = __builtin_amdgcn_mfma_f32_16x16x32_bf16(a_h[m], b_h,
                                                                    acc[m][n], 0, 0, 0);
                acc[m][n] = __builtin_amdgcn_mfma_f32_16x16x32_bf16(a_h[m], b_l,
                                                                    acc[m][n], 0, 0, 0);
                acc[m][n] = __builtin_amdgcn_mfma_f32_16x16x32_bf16(a_l[m], b_h,
                                                                    acc[m][n], 0, 0, 0);
            }
        }
    }

    // epilogue: local row lr = node_local*8 + t  ->  gx row t*Nn + node,
    // intra-row byte XOR-swizzled by (node&7)<<4; plain 2-byte stores
    #pragma unroll
    for (int n = 0; n < 6; ++n) {
        const int col = wc0 + n * 16 + l15;
        const float bb = bias[col];
        #pragma unroll
        for (int m = 0; m < 4; ++m) {
            #pragma unroll
            for (int q = 0; q < 4; ++q) {
                const int lr = m * 16 + l4 * 4 + q;
                const int tt = lr & 7;
                const int node = n0 + (lr >> 3);
                const size_t rowb = ((size_t)tt * Nn + node) * 768;
                const int cb = (col * 2) ^ ((node & 7) << 4);
                *(__half*)((char*)gx16 + rowb + cb) = __float2half(acc[m][n][q] + bb);
            }
        }
    }
}

// ---------------------------------------------------------------------------
// GRU v8: v6 structure (block = 32 nodes, 4 waves, register-local gate,
// h state in LDS, single node-group -> acc[2][6], 2 barriers/step, LDS 40KB
// -> 4 blocks/CU) + launch_bounds(256,1) so the allocator takes the VGPRs
// the live set needs (v6's only diagnosed flaw was (256,3) forcing 84 VGPR
// -> 1.3GB spill traffic; (256,1) proved the fix on v7).
// ---------------------------------------------------------------------------
__global__ __launch_bounds__(256, 1) void gru_kernel(const unsigned short* __restrict__ BTh,
                                                     const unsigned short* __restrict__ BTl,
                                                     const __half* __restrict__ gx,
                                                     const float* __restrict__ b_hh,
                                                     float* __restrict__ hbuf) {
    __shared__ __align__(16) char lds[40960];  // hHi 8K | hLo 8K | gxS 24K
    char* pHh = lds;
    char* pHl = lds + 8192;
    char* gxS = lds + 16384;
    const int tid = threadIdx.x;
    const int wid = tid >> 6, lane = tid & 63;
    const int l15 = lane & 15, l4 = lane >> 4;
    const int n0 = blockIdx.x * 32;

    float bh[3][2];
    #pragma unroll
    for (int g = 0; g < 3; ++g)
        #pragma unroll
        for (int tt = 0; tt < 2; ++tt)
            bh[g][tt] = b_hh[g * 128 + wid * 32 + tt * 16 + l15];

    #define ISSUE_GX(T)                                                                  \
        {                                                                                \
            const char* srcb = (const char*)(gx + ((size_t)(T) * Nn + n0) * 384);        \
            _Pragma("unroll")                                                            \
            for (int i = 0; i < 6; ++i) {                                                \
                const int o = i * 4096 + tid * 16;                                       \
                __builtin_amdgcn_global_load_lds(                                        \
                    (const __attribute__((address_space(1))) void*)(srcb + o),           \
                    (__attribute__((address_space(3))) void*)(gxS + o), 16, 0, 0);       \
            }                                                                            \
        }

    // ---- t = 0: gh = 0 (h=0); write h(0) to LDS only ----
    ISSUE_GX(0);
    __syncthreads();
    #pragma unroll
    for (int m = 0; m < 2; ++m) {
        #pragma unroll
        for (int q = 0; q < 4; ++q) {
            const int nl = m * 16 + l4 * 4 + q;
            const char* rp = gxS + nl * 768;
            const int key = (nl & 7) << 4;
            #pragma unroll
            for (int tt = 0; tt < 2; ++tt) {
                const int c0 = wid * 32 + tt * 16 + l15;
                float xr = __half2float(*(const __half*)(rp + ((2 * c0) ^ key)));
                float xz = __half2float(*(const __half*)(rp + ((2 * (c0 + 128)) ^ key)));
                float xn = __half2float(*(const __half*)(rp + ((2 * (c0 + 256)) ^ key)));
                float rg = 1.f / (1.f + expf(-(xr + bh[0][tt])));
                float zg = 1.f / (1.f + expf(-(xz + bh[1][tt])));
                float ng = tanhf(xn + rg * bh[2][tt]);
                float hnew = (1.f - zg) * ng;
                unsigned short sh, sl;
                split2(hnew, sh, sl);
                const int byteo = nl * 256 + ((2 * c0) ^ key);
                *(unsigned short*)(pHh + byteo) = sh;
                *(unsigned short*)(pHl + byteo) = sl;
            }
        }
    }

    for (int t = 1; t < Tt; ++t) {
        __syncthreads();  // gates of t-1 done (gxS reads retired, h(t-1) complete)
        ISSUE_GX(t);      // async: lands during MFMA

        const int wlast = (t == Tt - 1);
        // ---- MFMA: gh = h(t-1) @ W_hh^T, 32 rows x 192 cols per wave ----
        f32x4 acc[2][6];
        #pragma unroll
        for (int m = 0; m < 2; ++m)
            #pragma unroll
            for (int j = 0; j < 6; ++j) acc[m][j] = (f32x4){0.f, 0.f, 0.f, 0.f};
        const int akey = (l15 & 7) << 4;
        #pragma unroll
        for (int kq = 0; kq < 4; ++kq) {
            bf16x8 a_h[2], a_l[2];
            #pragma unroll
            for (int m = 0; m < 2; ++m) {
                const int ab = (m * 16 + l15) * 256 + ((kq * 64 + l4 * 16) ^ akey);
                a_h[m] = *(const bf16x8*)(pHh + ab);
                a_l[m] = *(const bf16x8*)(pHl + ab);
            }
            #pragma unroll
            for (int j = 0; j < 6; ++j) {
                const int g = j >> 1, tt = j & 1;
                const int col = g * 128 + wid * 32 + tt * 16 + l15;
                const size_t bo = (size_t)col * 128 + kq * 32 + l4 * 8;
                bf16x8 b_h = *(const bf16x8*)(BTh + bo);
                bf16x8 b_l = *(const bf16x8*)(BTl + bo);
                #pragma unroll
                for (int m = 0; m < 2; ++m) {
                    acc[m][j] = __builtin_amdgcn_mfma_f32_16x16x32_bf16(a_h[m], b_h,
                                                                       acc[m][j], 0, 0, 0);
                    acc[m][j] = __builtin_amdgcn_mfma_f32_16x16x32_bf16(a_h[m], b_l,
                                                                       acc[m][j], 0, 0, 0);
                    acc[m][j] = __builtin_amdgcn_mfma_f32_16x16x32_bf16(a_l[m], b_h,
                                                                       acc[m][j], 0, 0, 0);
                }
            }
        }
        __syncthreads();  // all MFMA h-reads done; vmcnt drained -> gx landed

        // ---- gate (register-local); h_old from LDS hi+lo ----
        #pragma unroll
        for (int m = 0; m < 2; ++m) {
            #pragma unroll
            for (int q = 0; q < 4; ++q) {
                const int nl = m * 16 + l4 * 4 + q;
                const char* rp = gxS + nl * 768;
                const int key = (nl & 7) << 4;
                #pragma unroll
                for (int tt = 0; tt < 2; ++tt) {
                    const int c0 = wid * 32 + tt * 16 + l15;
                    const int byteo = nl * 256 + ((2 * c0) ^ key);
                    float xr = __half2float(*(const __half*)(rp + ((2 * c0) ^ key)));
                    float xz = __half2float(*(const __half*)(rp + ((2 * (c0 + 128)) ^ key)));
                    float xn = __half2float(*(const __half*)(rp + ((2 * (c0 + 256)) ^ key)));
                    float h_old = bf2f(*(const unsigned short*)(pHh + byteo)) +
                                  bf2f(*(const unsigned short*)(pHl + byteo));
                    float ghr = acc[m][0 + tt][q] + bh[0][tt];
                    float ghz = acc[m][2 + tt][q] + bh[1][tt];
                    float ghn = acc[m][4 + tt][q] + bh[2][tt];
                    float rg = 1.f / (1.f + expf(-(xr + ghr)));
                    float zg = 1.f / (1.f + expf(-(xz + ghz)));
                    float ng = tanhf(xn + rg * ghn);
                    float hnew = (1.f - zg) * ng + zg * h_old;
                    if (!wlast) {
                        unsigned short sh, sl;
                        split2(hnew, sh, sl);
                        *(unsigned short*)(pHh + byteo) = sh;
                        *(unsigned short*)(pHl + byteo) = sl;
                    } else {
                        const int row = n0 + nl;
                        if (row < Nn) hbuf[(size_t)row * 128 + c0] = hnew;
                    }
                }
            }
        }
    }
    #undef ISSUE_GX
}

// ---------------------------------------------------------------------------
// Graph sizes by binary search on the SORTED batch array
// ---------------------------------------------------------------------------
__global__ void gcount_bs_kernel(const int* __restrict__ batch, float* __restrict__ ginv) {
    int g = threadIdx.x;
    if (g >= Gg) return;
    int lo = 0, hi = Nn;
    while (lo < hi) {
        int m = (lo + hi) >> 1;
        if (batch[m] < g) lo = m + 1; else hi = m;
    }
    int start = lo;
    lo = 0; hi = Nn;
    while (lo < hi) {
        int m = (lo + hi) >> 1;
        if (batch[m] <= g) lo = m + 1; else hi = m;
    }
    ginv[g] = 1.f / fmaxf((float)(lo - start), 1.f);
}

// ---------------------------------------------------------------------------
// FC (h @ W_fc + b_fc) fused with mean pooling via atomics
// ---------------------------------------------------------------------------
__global__ __launch_bounds__(256) void fc_pool_kernel(const float* __restrict__ h,
                                                      const float* __restrict__ Wfc,
                                                      const float* __restrict__ bfc,
                                                      const int* __restrict__ batch,
                                                      const float* __restrict__ ginv,
                                                      float* __restrict__ out) {
    __shared__ float hs[16][128];
    __shared__ float wf[128][10];
    __shared__ float bf[10];
    int b0 = blockIdx.x * 16;
    int t = threadIdx.x;
    for (int i = t; i < 128 * 10; i += 256) wf[i / 10][i % 10] = Wfc[i];
    if (t < 10) bf[t] = bfc[t];
    for (int i = t; i < 16 * 32; i += 256) {
        int r = i >> 5, c4 = i & 31;
        int row = b0 + r;
        float4 v = make_float4(0.f, 0.f, 0.f, 0.f);
        if (row < Nn) v = *(const float4*)(h + (size_t)row * 128 + c4 * 4);
        *(float4*)(&hs[r][c4 * 4]) = v;
    }
    __syncthreads();
    if (t < 160) {
        int r = t / 10, c = t % 10;
        int row = b0 + r;
        if (row < Nn) {
            float acc = bf[c];
            #pragma unroll
            for (int k = 0; k < 128; ++k) acc = fmaf(hs[r][k], wf[k][c], acc);
            int g = batch[row];
            atomicAdd(out + g * 10 + c, acc * ginv[g]);
        }
    }
}

// ---------------------------------------------------------------------------
// Launch
// ---------------------------------------------------------------------------
extern "C" void kernel_launch(void* const* d_in, const int* in_sizes, int n_in,
                              void* d_out, int out_size, void* d_ws, size_t ws_size,
                              hipStream_t stream) {
    const float* x_seq = (const float*)d_in[0];
    const int*   eidx  = (const int*)d_in[1];
    const int*   batch = (const int*)d_in[2];
    const float* W_gcn = (const float*)d_in[3];
    const float* b_gcn = (const float*)d_in[4];
    const float* W_ih  = (const float*)d_in[5];
    const float* W_hh  = (const float*)d_in[6];
    const float* b_ih  = (const float*)d_in[7];
    const float* b_hh  = (const float*)d_in[8];
    const float* W_fc  = (const float*)d_in[9];
    const float* b_fc  = (const float*)d_in[10];
    const int* src = eidx;
    const int* dst = eidx + Ee;
    float* out = (float*)d_out;

    size_t woff = 0;
    auto alloc = [&](size_t bytes) -> void* {
        void* p = (char*)d_ws + woff;
        woff = (woff + bytes + 255) & ~(size_t)255;
        return p;
    };
    int*   counts  = (int*)alloc(Nn * 4);
    int*   cursor  = (int*)alloc(Nn * 4);
    int*   incl    = (int*)alloc(Nn * 4);
    int*   blksum  = (int*)alloc(256 * 4);
    int*   offx    = (int*)alloc(Nn * 4);
    int*   csr_src = (int*)alloc(Ee * 4);
    float* csr_w   = (float*)alloc(Ee * 4);
    float* dis     = (float*)alloc(Nn * 4);
    unsigned short* wg_hi  = (unsigned short*)alloc(128 * 128 * 2);
    unsigned short* wg_lo  = (unsigned short*)alloc(128 * 128 * 2);
    unsigned short* wih_hi = (unsigned short*)alloc(384 * 128 * 2);
    unsigned short* wih_lo = (unsigned short*)alloc(384 * 128 * 2);
    unsigned short* whh_hi = (unsigned short*)alloc(384 * 128 * 2);
    unsigned short* whh_lo = (unsigned short*)alloc(384 * 128 * 2);
    float* ginv = (float*)alloc(256);
    __half* xwp  = (__half*)alloc((size_t)NT * 128 * 2);  // 102.4 MB fp16, [n][t][128]
    __half* gx16 = (__half*)alloc((size_t)NT * 384 * 2);  // 307.2 MB, [t][n][384] swz
    float* hbuf  = (float*)alloc((size_t)Nn * 128 * 4);   // 25.6 MB (also DMA tail pad)

    hipMemsetAsync(counts, 0, Nn * 4, stream);
    hipMemsetAsync(cursor, 0, Nn * 4, stream);
    hipMemsetAsync(d_out, 0, (size_t)Gg * Cc * 4, stream);

    const int nbN = (Nn + 255) / 256;
    const int nbE = (Ee + 255) / 256;

    count_deg_kernel<<<nbE, 256, 0, stream>>>(dst, counts);
    dis_kernel<<<nbN, 256, 0, stream>>>(counts, dis);
    scan_block_kernel<<<nbN, 256, 0, stream>>>(counts, incl, blksum);
    scan_tops_kernel<<<1, 256, 0, stream>>>(blksum, nbN);
    scan_fix_kernel<<<nbN, 256, 0, stream>>>(counts, incl, blksum, offx);
    fill_csr_kernel<<<nbE, 256, 0, stream>>>(src, dst, dis, offx, cursor, csr_src, csr_w);

    wsplit_kernel<<<(384 * 128 + 255) / 256, 256, 0, stream>>>(W_ih, wih_hi, wih_lo, 384 * 128);
    wsplit_kernel<<<(384 * 128 + 255) / 256, 256, 0, stream>>>(W_hh, whh_hi, whh_lo, 384 * 128);
    wgcnT_kernel<<<(128 * 128 + 255) / 256, 256, 0, stream>>>(W_gcn, wg_hi, wg_lo);
    gcount_bs_kernel<<<1, 64, 0, stream>>>(batch, ginv);

    // xw for all T, output [n][t][128] fp16 (L3-resident gather source)
    xw_gemm<<<NT / 128, 256, 0, stream>>>(x_seq, wg_hi, wg_lo, xwp);
    // fused aggregation + gx GEMM (round-15/19 best config)
    aggx_kernel<<<Nn / 8, 256, 0, stream>>>(xwp, dis, offx, counts, csr_src, csr_w,
                                            b_gcn, wih_hi, wih_lo, b_ih, gx16);
    // GRU v8: 32-node blocks + (256,1) -> 4 blocks/CU, no spills
    gru_kernel<<<(Nn + 31) / 32, 256, 0, stream>>>(whh_hi, whh_lo, gx16, b_hh, hbuf);

    fc_pool_kernel<<<(Nn + 15) / 16, 256, 0, stream>>>(hbuf, W_fc, b_fc, batch, ginv, out);
}